// Round 6
// baseline (726.044 us; speedup 1.0000x reference)
//
#include <hip/hip_runtime.h>

typedef unsigned short u16;
typedef __bf16 bf16_t;
typedef bf16_t bf16x8 __attribute__((ext_vector_type(8)));
typedef float f32x4 __attribute__((ext_vector_type(4)));
typedef u16 u16x4 __attribute__((ext_vector_type(4)));

#define MODE_PLAIN 0
#define MODE_FUSEQT 1
#define MODE_PARTIAL 2
#define MODE_SFIN 3
#define MODE_CVT 4
#define MODE_INIT 5
#define MODE_TRANS 6

#define SLC 2097152L   // 4096*512

__device__ __forceinline__ float bf2f(u16 u) {
  unsigned int x = ((unsigned int)u) << 16;
  return __builtin_bit_cast(float, x);
}
__device__ __forceinline__ u16 f2bf(float f) {
  unsigned int x = __builtin_bit_cast(unsigned int, f);
  x += 0x7fffu + ((x >> 16) & 1u);
  return (u16)(x >> 16);
}

__device__ __forceinline__ void gload_lds16(const void* g, void* l) {
  __builtin_amdgcn_global_load_lds(
      (const __attribute__((address_space(1))) void*)g,
      (__attribute__((address_space(3))) void*)l, 16, 0, 0);
}

struct Job {
  int mode, gx, gy, ksl;          // gemm grid (x-major-outer decode), log2 K-chunks
  const u16 *A0, *A1, *B; long bz;
  const float *Bf, *Bf2;          // f32 B (pair-summed if Bf2) — overrides B
  int lda, ldb, K;                // K = per-chunk K
  u16 *C; long cfz; int ldc;      // PLAIN dst / TRANS dst(+z-stride)
  u16 *XwT, *TTp, *Pn;            // FUSEQT
  float *Cf; int ldcf;            // PARTIAL: Cf[zi*cfz + row*ldcf + col]
  const float *Ef, *Up; u16 *Yc;  // SFIN
  const float *S0, *S1; u16 *D0;  // CVT / INIT
};
struct LaunchP { Job j[3]; int s1, s2; };

__device__ __forceinline__ void run_job(const Job& p, int rb, u16* smem) {
  const int tid = threadIdx.x;

  if (p.mode == MODE_CVT) {       // adj/adj1 f32 -> adjb bf16 (512 blocks)
    const float* src = (rb < 256) ? p.S0 : p.S1;
    u16* dst = p.D0 + ((rb < 256) ? 0L : 16777216L);
    int r = rb & 255;
#pragma unroll 4
    for (int i = 0; i < 64; ++i) {
      long idx = (long)i * 65536 + r * 256 + tid;
      f32x4 v = ((const f32x4*)src)[idx];
      u16x4 o;
#pragma unroll
      for (int k = 0; k < 4; ++k) o[k] = f2bf(v[k]);
      ((u16x4*)dst)[idx] = o;
    }
    return;
  }
  if (p.mode == MODE_INIT) {      // y,feat f32 -> Ycat bf16 x3 (256 blocks)
#pragma unroll
    for (int i = 0; i < 8; ++i) {
      long idx = (long)i * 65536 + rb * 256 + tid;
      f32x4 a = ((const f32x4*)p.S0)[idx];
      f32x4 f = ((const f32x4*)p.S1)[idx];
      u16x4 ua, uf;
#pragma unroll
      for (int k = 0; k < 4; ++k) { ua[k] = f2bf(a[k]); uf[k] = f2bf(f[k]); }
      ((u16x4*)p.D0)[idx] = ua;
      ((u16x4*)p.D0)[idx + 524288] = uf;
      ((u16x4*)p.D0)[idx + 1048576] = uf;
    }
    return;
  }
  if (p.mode == MODE_TRANS) {     // [4096,512] -> [512,4096], 64x64 tiles, z in {0,1}
    u16 (*t)[68] = (u16(*)[68])smem;
    int zi = rb >> 9, rem = rb & 511;
    int bx = rem >> 6, by = rem & 63;
    const u16* src = p.A0 + (long)zi * p.bz;
    u16* dst = p.C + (long)zi * p.cfz;
    int tr = tid >> 4, tc = (tid & 15) * 4;
    long r0 = (long)by * 64, c0 = (long)bx * 64;
#pragma unroll
    for (int i = 0; i < 4; ++i) {
      int r = i * 16 + tr;
      uint2 v = *(const uint2*)(src + (r0 + r) * 512 + c0 + tc);
      t[r][tc] = (u16)(v.x & 0xffff); t[r][tc + 1] = (u16)(v.x >> 16);
      t[r][tc + 2] = (u16)(v.y & 0xffff); t[r][tc + 3] = (u16)(v.y >> 16);
    }
    __syncthreads();
#pragma unroll
    for (int i = 0; i < 4; ++i) {
      int r = i * 16 + tr;
      unsigned int a0 = t[tc + 0][r], a1 = t[tc + 1][r], a2 = t[tc + 2][r], a3 = t[tc + 3][r];
      uint2 v; v.x = a0 | (a1 << 16); v.y = a2 | (a3 << 16);
      *(uint2*)(dst + (c0 + r) * 4096 + r0 + tc) = v;
    }
    return;
  }

  // ---- gemm: C[m][n] = sum_k A[m][k]*B[n][k] ----
  const int lane = tid & 63, wave = tid >> 6;
  int per = p.gx * p.gy;
  int zi = rb / per, rem = rb - zi * per;
  int bx = rem / p.gy, by = rem - bx * p.gy;   // x-major-outer: same-tileM blocks gy apart
  int z = zi >> p.ksl, kc = zi & ((1 << p.ksl) - 1);
  const long tileM = (long)by * 128;
  const long tileN = (long)bx * 128;
  u16* ldsA = smem;
  u16* ldsB = smem + 128 * 64;

  const u16* A = (z == 0) ? p.A0 : p.A1;
  const u16* B = p.B + (long)z * p.bz;
  const float* Bf = p.Bf;

  const int srow = wave * 8 + (lane >> 3);
  const int ssc = lane & 7;
  long aoff[4], boff[4];
#pragma unroll
  for (int j = 0; j < 4; ++j) {
    int r = j * 32 + srow;
    int c = ssc ^ (r & 7);               // XOR swizzle: LDS[r][ssc] holds global chunk c
    aoff[j] = ((tileM + r) * (long)p.lda + c * 8) * 2;
    boff[j] = ((tileN + r) * (long)p.ldb + c * 8) * 2;
  }
  const int frow = tid >> 4, fcol = tid & 15;  // f32 staging coords

  const int r15 = lane & 15, q = lane >> 4;
  const int wm = (wave & 1) * 64, wn = (wave >> 1) * 64;

  f32x4 acc[4][4];
#pragma unroll
  for (int i = 0; i < 4; ++i)
#pragma unroll
    for (int j = 0; j < 4; ++j) { f32x4 zz = {0.f, 0.f, 0.f, 0.f}; acc[i][j] = zz; }

  const int K64 = p.K >> 6;
  const long kofs = (long)kc * K64;
  for (int kt = 0; kt < K64; ++kt) {
    const long kb = (kofs + kt) * 128;
    __syncthreads();
#pragma unroll
    for (int j = 0; j < 4; ++j)
      gload_lds16((const char*)A + aoff[j] + kb, (char*)ldsA + (j * 256 + wave * 64) * 16);
    if (Bf) {
#pragma unroll
      for (int i = 0; i < 8; ++i) {
        int r = i * 16 + frow;
        long gi = (tileN + r) * (long)p.ldb + (kofs + kt) * 64 + fcol * 4;
        f32x4 v = *(const f32x4*)(Bf + gi);
        if (p.Bf2) v += *(const f32x4*)(p.Bf2 + gi);
        int sc = (fcol >> 1) ^ (r & 7);
        u16x4 o; o[0] = f2bf(v[0]); o[1] = f2bf(v[1]); o[2] = f2bf(v[2]); o[3] = f2bf(v[3]);
        *(u16x4*)(ldsB + (r * 8 + sc) * 8 + (fcol & 1) * 4) = o;
      }
    } else {
#pragma unroll
      for (int j = 0; j < 4; ++j)
        gload_lds16((const char*)B + boff[j] + kb, (char*)ldsB + (j * 256 + wave * 64) * 16);
    }
    __syncthreads();
#pragma unroll
    for (int ks = 0; ks < 2; ++ks) {
      bf16x8 af[4], bfr[4];
#pragma unroll
      for (int mt = 0; mt < 4; ++mt) {
        int row = wm + mt * 16 + r15;
        int sc = (ks * 4 + q) ^ (r15 & 7);
        af[mt] = *(const bf16x8*)(ldsA + (row * 8 + sc) * 8);
      }
#pragma unroll
      for (int nt = 0; nt < 4; ++nt) {
        int row = wn + nt * 16 + r15;
        int sc = (ks * 4 + q) ^ (r15 & 7);
        bfr[nt] = *(const bf16x8*)(ldsB + (row * 8 + sc) * 8);
      }
#pragma unroll
      for (int mt = 0; mt < 4; ++mt)
#pragma unroll
        for (int nt = 0; nt < 4; ++nt)
          acc[mt][nt] = __builtin_amdgcn_mfma_f32_16x16x32_bf16(af[mt], bfr[nt], acc[mt][nt], 0, 0, 0);
    }
  }

  // epilogue — C/D layout: col = lane&15, row = (lane>>4)*4 + reg  [m89-verified]
  const int mode = p.mode;
#pragma unroll
  for (int mt = 0; mt < 4; ++mt) {
#pragma unroll
    for (int nt = 0; nt < 4; ++nt) {
      long row0 = tileM + wm + mt * 16 + q * 4;
      long col = tileN + wn + nt * 16 + r15;
      if (mode == MODE_FUSEQT) {
        long bm = row0 >> 12, n0 = row0 & 4095;
        u16x4 ov;
#pragma unroll
        for (int r = 0; r < 4; ++r) ov[r] = f2bf(acc[mt][nt][r]);
        if (col < 512) {
          *(u16x4*)(p.XwT + (bm * 512 + col) * 4096 + n0) = ov;   // Q^T block
          float s = (bm == 0) ? 1.f : -0.5f;
          u16* pn = p.Pn + n0 * 1536 + bm * 512 + col;
#pragma unroll
          for (int r = 0; r < 4; ++r) pn[(long)r * 1536] = f2bf(s * acc[mt][nt][r]);
        } else {
          *(u16x4*)(p.TTp + (bm * 512 + (col - 512)) * 4096 + n0) = ov;  // T^T block
        }
      } else if (mode == MODE_PARTIAL) {
        float* c = p.Cf + (long)zi * p.cfz + row0 * p.ldcf + col;
#pragma unroll
        for (int r = 0; r < 4; ++r) c[(long)r * p.ldcf] = acc[mt][nt][r];
      } else if (mode == MODE_SFIN) {
        long b = col >> 9, f = col & 511;
#pragma unroll
        for (int r = 0; r < 4; ++r) {
          long row = row0 + r;
          float v = acc[mt][nt][r];
          float o;
          if (b == 0) {
            o = p.Ef[row * 512 + f] - 0.5f * (1.f / (1.f + __expf(-v)));
          } else {
            const float* u = p.Up + (b - 1) * 2 * SLC + row * 512 + f;
            float e = u[0] + u[SLC];
            o = e - 0.25f * (1.f / (1.f + __expf(v)));   // sigmoid(-v)
          }
          p.Yc[b * SLC + row * 512 + f] = f2bf(o);
        }
      } else {  // MODE_PLAIN
#pragma unroll
        for (int r = 0; r < 4; ++r)
          p.C[(row0 + r) * (long)p.ldc + col] = f2bf(acc[mt][nt][r]);
      }
    }
  }
}

__global__ __launch_bounds__(256) void fused_k(LaunchP lp) {
  __shared__ u16 smem[2 * 128 * 64];
  int bid = blockIdx.x;
  if (bid < lp.s1) run_job(lp.j[0], bid, smem);
  else if (bid < lp.s2) run_job(lp.j[1], bid - lp.s1, smem);
  else run_job(lp.j[2], bid - lp.s2, smem);
}

// ---- small standalone kernels ----

__global__ __launch_bounds__(256) void pack_m2_k(const float* wy, u16* M2, u16* Bcat) {
  int idx = blockIdx.x * 256 + threadIdx.x;   // 0..262143
  int i = idx >> 9, j = idx & 511;
  u16 a = f2bf(wy[idx]);
  u16 b = f2bf(wy[(long)j * 512 + i]);
  M2[(long)i * 1024 + j] = a;          // [wy | wy^T]
  M2[(long)i * 1024 + 512 + j] = b;
  Bcat[(long)i * 512 + j] = b;         // rows 0..511 of Bcat = wy^T
}

__device__ __forceinline__ float waveRedSum(float v) {
#pragma unroll
  for (int o = 32; o > 0; o >>= 1) v += __shfl_down(v, o, 64);
  return v;
}
__device__ __forceinline__ float waveRedMax(float v) {
#pragma unroll
  for (int o = 32; o > 0; o >>= 1) v = fmaxf(v, __shfl_down(v, o, 64));
  return v;
}

__global__ __launch_bounds__(256) void l2norm_k(const u16* Ycat, u16* pb) {
  __shared__ float red[4];
  int i = blockIdx.x, b = blockIdx.y, t = threadIdx.x;
  const u16* row = Ycat + ((long)b * 4096 + (long)i) * 512;
  unsigned int v = *(const unsigned int*)(row + 2 * t);
  float x0 = bf2f((u16)(v & 0xffff)), x1 = bf2f((u16)(v >> 16));
  float w = waveRedSum(x0 * x0 + x1 * x1);
  if ((t & 63) == 0) red[t >> 6] = w;
  __syncthreads();
  float tot = red[0] + red[1] + red[2] + red[3];
  float inv = 1.f / fmaxf(sqrtf(tot), 1e-12f);
  unsigned int o = (unsigned int)f2bf(x0 * inv) | ((unsigned int)f2bf(x1 * inv) << 16);
  *(unsigned int*)(pb + (long)i * 1536 + b * 512 + 2 * t) = o;
}

// sums 4 split-K logit partials + bias, then log_softmax
__global__ __launch_bounds__(256) void logsoftmax_k(const float* lg, const float* bias, float* out) {
  __shared__ float red[4];
  int i = blockIdx.x, t = threadIdx.x;
  const float* row = lg + (long)i * 512;
  float a  = row[t]       + row[t + SLC]       + row[t + 2 * SLC]       + row[t + 3 * SLC]       + bias[t];
  float b2 = row[t + 256] + row[t + 256 + SLC] + row[t + 256 + 2 * SLC] + row[t + 256 + 3 * SLC] + bias[t + 256];
  float m = waveRedMax(fmaxf(a, b2));
  if ((t & 63) == 0) red[t >> 6] = m;
  __syncthreads();
  float M = fmaxf(fmaxf(red[0], red[1]), fmaxf(red[2], red[3]));
  __syncthreads();
  float w = waveRedSum(__expf(a - M) + __expf(b2 - M));
  if ((t & 63) == 0) red[t >> 6] = w;
  __syncthreads();
  float S = red[0] + red[1] + red[2] + red[3];
  float lse = M + __logf(S);
  out[(long)i * 512 + t] = a - lse;
  out[(long)i * 512 + t + 256] = b2 - lse;
}

extern "C" void kernel_launch(void* const* d_in, const int* in_sizes, int n_in,
                              void* d_out, int out_size, void* d_ws, size_t ws_size,
                              hipStream_t stream) {
  const float* feat = (const float*)d_in[0];
  const float* adj  = (const float*)d_in[1];
  const float* adj1 = (const float*)d_in[2];
  const float* y    = (const float*)d_in[3];
  const float* wy   = (const float*)d_in[4];
  const float* w2w  = (const float*)d_in[5];
  const float* w2b  = (const float*)d_in[6];
  (void)in_sizes; (void)n_in; (void)out_size; (void)ws_size;

  char* ws = (char*)d_ws;
  size_t off = 0;
  auto alloc = [&](size_t bytes) -> void* {
    void* r = ws + off; off += (bytes + 255) & ~(size_t)255; return r;
  };
  u16* M2   = (u16*)alloc(512L * 1024 * 2);        // [wy | wy^T]
  u16* Bcat = (u16*)alloc(1024L * 512 * 2);        // [wy^T rows | Wsum rows]
  u16* adjb = (u16*)alloc(2L * 4096 * 4096 * 2);   // bf16 adj, adj1
  u16* Ycat = (u16*)alloc(3L * 4096 * 512 * 2);    // y,z1,z2 node-major
  u16* Pn   = (u16*)alloc(4096L * 1536 * 2);       // P node-major (scaled)
  u16* XwT  = (u16*)alloc(3L * 512 * 4096 * 2);    // (Ycat@wy)^T; later pb
  u16* TT   = (u16*)alloc(3L * 512 * 4096 * 2);    // (Ycat@Wsum)^T
  u16* Zt   = (u16*)alloc(2L * 512 * 4096 * 2);    // z1^T,z2^T
  float* Wp = (float*)alloc(2L * 1536 * 1536 * 4); // W^T split-K f32 partials
  float* WU = (float*)alloc(4L * SLC * 4);         // U partials / logit partials
  u16* pb = XwT;
  const long WSL = 1536L * 1536;

  pack_m2_k<<<1024, 256, 0, stream>>>(wy, M2, Bcat);

  { LaunchP lp = {};   // CVT (512) || INIT (256) || Wsum gemm (16)
    Job& a = lp.j[0]; a.mode = MODE_CVT; a.S0 = adj; a.S1 = adj1; a.D0 = adjb;
    Job& b = lp.j[1]; b.mode = MODE_INIT; b.S0 = y; b.S1 = feat; b.D0 = Ycat;
    Job& c = lp.j[2]; c.mode = MODE_PLAIN; c.gx = 4; c.gy = 4; c.K = 1024;
    c.A0 = c.A1 = M2; c.B = M2; c.lda = 1024; c.ldb = 1024;
    c.C = Bcat + 512L * 512; c.ldc = 512;
    lp.s1 = 512; lp.s2 = 768;
    fused_k<<<784, 256, 0, stream>>>(lp); }

  for (int L = 0; L < 2; ++L) {
    { LaunchP lp = {};   // FUSEQT (768) || TRANS (1024)
      Job& a = lp.j[0]; a.mode = MODE_FUSEQT; a.gx = 8; a.gy = 96; a.K = 512;
      a.A0 = a.A1 = Ycat; a.B = Bcat; a.lda = 512; a.ldb = 512;
      a.XwT = XwT; a.TTp = TT; a.Pn = Pn;
      Job& b = lp.j[1]; b.mode = MODE_TRANS; b.A0 = Ycat + SLC; b.bz = SLC;
      b.C = Zt; b.cfz = SLC;
      lp.s1 = 768; lp.s2 = 1792;
      fused_k<<<1792, 256, 0, stream>>>(lp); }

    { LaunchP lp = {};   // U partials (512, split-K2) || Wt partials (288, split-K2)
      // all 800 blocks do exactly 32 k-tiles -> no tail imbalance
      Job& a = lp.j[0]; a.mode = MODE_PARTIAL; a.gx = 4; a.gy = 32; a.ksl = 1; a.K = 2048;
      a.A0 = adjb; a.A1 = adjb + 16777216L; a.B = Zt; a.bz = SLC;
      a.lda = 4096; a.ldb = 4096; a.Cf = WU; a.cfz = SLC; a.ldcf = 512;
      Job& b = lp.j[1]; b.mode = MODE_PARTIAL; b.gx = 12; b.gy = 12; b.ksl = 1; b.K = 2048;
      b.A0 = b.A1 = TT; b.B = XwT; b.lda = 4096; b.ldb = 4096;
      b.Cf = Wp; b.cfz = WSL; b.ldcf = 1536;
      lp.s1 = 512; lp.s2 = 800;
      fused_k<<<800, 256, 0, stream>>>(lp); }

    { LaunchP lp = {};   // SFIN: S = Pn @ (Wp0+Wp1)^T, fused sigmoid updates into Ycat
      Job& a = lp.j[0]; a.mode = MODE_SFIN; a.gx = 12; a.gy = 32; a.K = 1536;
      a.A0 = a.A1 = Pn; a.Bf = Wp; a.Bf2 = Wp + WSL; a.lda = 1536; a.ldb = 1536;
      a.Ef = feat; a.Up = WU; a.Yc = Ycat;
      lp.s1 = 384; lp.s2 = 384;
      fused_k<<<384, 256, 0, stream>>>(lp); }
  }

  l2norm_k<<<dim3(4096, 3, 1), 256, 0, stream>>>(Ycat, pb);

  { LaunchP lp = {};   // logits split-K4 partials (512 blocks)
    Job& a = lp.j[0]; a.mode = MODE_PARTIAL; a.gx = 4; a.gy = 32; a.ksl = 2; a.K = 384;
    a.A0 = a.A1 = pb; a.Bf = w2w; a.lda = 1536; a.ldb = 1536;
    a.Cf = WU; a.cfz = SLC; a.ldcf = 512;
    lp.s1 = 512; lp.s2 = 512;
    fused_k<<<512, 256, 0, stream>>>(lp); }

  logsoftmax_k<<<4096, 256, 0, stream>>>(WU, w2b, (float*)d_out);
}

// Round 7
// 705.727 us; speedup vs baseline: 1.0288x; 1.0288x over previous
//
#include <hip/hip_runtime.h>

typedef unsigned short u16;
typedef __bf16 bf16_t;
typedef bf16_t bf16x8 __attribute__((ext_vector_type(8)));
typedef float f32x4 __attribute__((ext_vector_type(4)));
typedef u16 u16x4 __attribute__((ext_vector_type(4)));

#define MODE_PLAIN 0
#define MODE_FUSEQT 1
#define MODE_PARTIAL 2
#define MODE_SFIN 3
#define MODE_CVT 4
#define MODE_INIT 5
#define MODE_TRANS 6

#define SLC 2097152L   // 4096*512

__device__ __forceinline__ float bf2f(u16 u) {
  unsigned int x = ((unsigned int)u) << 16;
  return __builtin_bit_cast(float, x);
}
__device__ __forceinline__ u16 f2bf(float f) {
  unsigned int x = __builtin_bit_cast(unsigned int, f);
  x += 0x7fffu + ((x >> 16) & 1u);
  return (u16)(x >> 16);
}

__device__ __forceinline__ void gload_lds16(const void* g, void* l) {
  __builtin_amdgcn_global_load_lds(
      (const __attribute__((address_space(1))) void*)g,
      (__attribute__((address_space(3))) void*)l, 16, 0, 0);
}

struct Job {
  int mode, gx, gy, ksl;          // gemm grid, log2 K-chunks; gx%4==0, gy%4==0
  const u16 *A0, *A1, *B; long bz;
  const float *Bf;                // f32 B (logits) — overrides B
  int lda, ldb, K;                // K = per-chunk K
  u16 *C; long cfz; int ldc;      // PLAIN dst / TRANS dst(+z-stride)
  u16 *XwT, *TTp, *Pn;            // FUSEQT
  float *Cf; int ldcf;            // PARTIAL: Cf[zi*cfz + row*ldcf + col]
  const float *Ef, *Up; u16 *Yc;  // SFIN
  const float *S0, *S1; u16 *D0;  // CVT / INIT
};
struct LaunchP { Job j[3]; int s1, s2; };

__device__ __forceinline__ void run_job(const Job& p, int rb, u16* smem) {
  const int tid = threadIdx.x;

  if (p.mode == MODE_CVT) {       // adj/adj1 f32 -> adjb bf16 (512 blocks)
    const float* src = (rb < 256) ? p.S0 : p.S1;
    u16* dst = p.D0 + ((rb < 256) ? 0L : 16777216L);
    int r = rb & 255;
#pragma unroll 4
    for (int i = 0; i < 64; ++i) {
      long idx = (long)i * 65536 + r * 256 + tid;
      f32x4 v = ((const f32x4*)src)[idx];
      u16x4 o;
#pragma unroll
      for (int k = 0; k < 4; ++k) o[k] = f2bf(v[k]);
      ((u16x4*)dst)[idx] = o;
    }
    return;
  }
  if (p.mode == MODE_INIT) {      // y,feat f32 -> Ycat bf16 x3 (256 blocks)
#pragma unroll
    for (int i = 0; i < 8; ++i) {
      long idx = (long)i * 65536 + rb * 256 + tid;
      f32x4 a = ((const f32x4*)p.S0)[idx];
      f32x4 f = ((const f32x4*)p.S1)[idx];
      u16x4 ua, uf;
#pragma unroll
      for (int k = 0; k < 4; ++k) { ua[k] = f2bf(a[k]); uf[k] = f2bf(f[k]); }
      ((u16x4*)p.D0)[idx] = ua;
      ((u16x4*)p.D0)[idx + 524288] = uf;
      ((u16x4*)p.D0)[idx + 1048576] = uf;
    }
    return;
  }
  if (p.mode == MODE_TRANS) {     // [4096,512] -> [512,4096], 64x64 tiles, z in {0,1}
    u16 (*t)[68] = (u16(*)[68])smem;
    int zi = rb >> 9, rem = rb & 511;
    int bx = rem >> 6, by = rem & 63;
    const u16* src = p.A0 + (long)zi * p.bz;
    u16* dst = p.C + (long)zi * p.cfz;
    int tr = tid >> 4, tc = (tid & 15) * 4;
    long r0 = (long)by * 64, c0 = (long)bx * 64;
#pragma unroll
    for (int i = 0; i < 4; ++i) {
      int r = i * 16 + tr;
      uint2 v = *(const uint2*)(src + (r0 + r) * 512 + c0 + tc);
      t[r][tc] = (u16)(v.x & 0xffff); t[r][tc + 1] = (u16)(v.x >> 16);
      t[r][tc + 2] = (u16)(v.y & 0xffff); t[r][tc + 3] = (u16)(v.y >> 16);
    }
    __syncthreads();
#pragma unroll
    for (int i = 0; i < 4; ++i) {
      int r = i * 16 + tr;
      unsigned int a0 = t[tc + 0][r], a1 = t[tc + 1][r], a2 = t[tc + 2][r], a3 = t[tc + 3][r];
      uint2 v; v.x = a0 | (a1 << 16); v.y = a2 | (a3 << 16);
      *(uint2*)(dst + (c0 + r) * 4096 + r0 + tc) = v;
    }
    return;
  }

  // ---- gemm: C[m][n] = sum_k A[m][k]*B[n][k] ----
  const int lane = tid & 63, wave = tid >> 6;
  int per = p.gx * p.gy;
  int zi = rb / per, rem = rb - zi * per;
  // 4x4 supertile swizzle: 16 consecutive ids = 4 A-panels x 4 B-panels,
  // spread round-robin over the 8 XCDs -> per-XCD L2 hot set ~2MB.
  int sx = p.gx >> 2;
  int st = rem >> 4, t4 = rem & 15;
  int bx = (st % sx) * 4 + (t4 & 3);
  int by = (st / sx) * 4 + (t4 >> 2);
  int z = zi >> p.ksl, kc = zi & ((1 << p.ksl) - 1);
  const long tileM = (long)by * 128;
  const long tileN = (long)bx * 128;
  u16* ldsA = smem;
  u16* ldsB = smem + 128 * 64;

  const u16* A = (z == 0) ? p.A0 : p.A1;
  const u16* B = p.B + (long)z * p.bz;
  const float* Bf = p.Bf;

  const int srow = wave * 8 + (lane >> 3);
  const int ssc = lane & 7;
  long aoff[4], boff[4];
#pragma unroll
  for (int j = 0; j < 4; ++j) {
    int r = j * 32 + srow;
    int c = ssc ^ (r & 7);               // XOR swizzle: LDS[r][ssc] holds global chunk c
    aoff[j] = ((tileM + r) * (long)p.lda + c * 8) * 2;
    boff[j] = ((tileN + r) * (long)p.ldb + c * 8) * 2;
  }
  const int frow = tid >> 4, fcol = tid & 15;  // f32 staging coords

  const int r15 = lane & 15, q = lane >> 4;
  const int wm = (wave & 1) * 64, wn = (wave >> 1) * 64;

  f32x4 acc[4][4];
#pragma unroll
  for (int i = 0; i < 4; ++i)
#pragma unroll
    for (int j = 0; j < 4; ++j) { f32x4 zz = {0.f, 0.f, 0.f, 0.f}; acc[i][j] = zz; }

  const int K64 = p.K >> 6;
  const long kofs = (long)kc * K64;
  for (int kt = 0; kt < K64; ++kt) {
    const long kb = (kofs + kt) * 128;
    __syncthreads();
#pragma unroll
    for (int j = 0; j < 4; ++j)
      gload_lds16((const char*)A + aoff[j] + kb, (char*)ldsA + (j * 256 + wave * 64) * 16);
    if (Bf) {
#pragma unroll
      for (int i = 0; i < 8; ++i) {
        int r = i * 16 + frow;
        f32x4 v = *(const f32x4*)(Bf + (tileN + r) * (long)p.ldb + (kofs + kt) * 64 + fcol * 4);
        int sc = (fcol >> 1) ^ (r & 7);
        u16x4 o; o[0] = f2bf(v[0]); o[1] = f2bf(v[1]); o[2] = f2bf(v[2]); o[3] = f2bf(v[3]);
        *(u16x4*)(ldsB + (r * 8 + sc) * 8 + (fcol & 1) * 4) = o;
      }
    } else {
#pragma unroll
      for (int j = 0; j < 4; ++j)
        gload_lds16((const char*)B + boff[j] + kb, (char*)ldsB + (j * 256 + wave * 64) * 16);
    }
    __syncthreads();
#pragma unroll
    for (int ks = 0; ks < 2; ++ks) {
      bf16x8 af[4], bfr[4];
#pragma unroll
      for (int mt = 0; mt < 4; ++mt) {
        int row = wm + mt * 16 + r15;
        int sc = (ks * 4 + q) ^ (r15 & 7);
        af[mt] = *(const bf16x8*)(ldsA + (row * 8 + sc) * 8);
      }
#pragma unroll
      for (int nt = 0; nt < 4; ++nt) {
        int row = wn + nt * 16 + r15;
        int sc = (ks * 4 + q) ^ (r15 & 7);
        bfr[nt] = *(const bf16x8*)(ldsB + (row * 8 + sc) * 8);
      }
#pragma unroll
      for (int mt = 0; mt < 4; ++mt)
#pragma unroll
        for (int nt = 0; nt < 4; ++nt)
          acc[mt][nt] = __builtin_amdgcn_mfma_f32_16x16x32_bf16(af[mt], bfr[nt], acc[mt][nt], 0, 0, 0);
    }
  }

  // epilogue — C/D layout: col = lane&15, row = (lane>>4)*4 + reg  [m89-verified]
  const int mode = p.mode;
#pragma unroll
  for (int mt = 0; mt < 4; ++mt) {
#pragma unroll
    for (int nt = 0; nt < 4; ++nt) {
      long row0 = tileM + wm + mt * 16 + q * 4;
      long col = tileN + wn + nt * 16 + r15;
      if (mode == MODE_FUSEQT) {
        long bm = row0 >> 12, n0 = row0 & 4095;
        u16x4 ov;
#pragma unroll
        for (int r = 0; r < 4; ++r) ov[r] = f2bf(acc[mt][nt][r]);
        if (col < 512) {
          *(u16x4*)(p.XwT + (bm * 512 + col) * 4096 + n0) = ov;   // Q^T block
          float s = (bm == 0) ? 1.f : -0.5f;
          u16* pn = p.Pn + n0 * 1536 + bm * 512 + col;
#pragma unroll
          for (int r = 0; r < 4; ++r) pn[(long)r * 1536] = f2bf(s * acc[mt][nt][r]);
        } else {
          *(u16x4*)(p.TTp + (bm * 512 + (col - 512)) * 4096 + n0) = ov;  // T^T block
        }
      } else if (mode == MODE_PARTIAL) {
        float* c = p.Cf + (long)zi * p.cfz + row0 * p.ldcf + col;
#pragma unroll
        for (int r = 0; r < 4; ++r) c[(long)r * p.ldcf] = acc[mt][nt][r];
      } else if (mode == MODE_SFIN) {
        long b = col >> 9, f = col & 511;
#pragma unroll
        for (int r = 0; r < 4; ++r) {
          long row = row0 + r;
          float v = acc[mt][nt][r];
          float o;
          if (b == 0) {
            o = p.Ef[row * 512 + f] - 0.5f * (1.f / (1.f + __expf(-v)));
          } else {
            const float* u = p.Up + (b - 1) * 2 * SLC + row * 512 + f;
            float e = u[0] + u[SLC];
            o = e - 0.25f * (1.f / (1.f + __expf(v)));   // sigmoid(-v)
          }
          p.Yc[b * SLC + row * 512 + f] = f2bf(o);
        }
      } else {  // MODE_PLAIN
#pragma unroll
        for (int r = 0; r < 4; ++r)
          p.C[(row0 + r) * (long)p.ldc + col] = f2bf(acc[mt][nt][r]);
      }
    }
  }
}

// distinct name per launch slot so rocprof rows are attributable
template <int TAG>
__global__ __launch_bounds__(256) void fused_kt(LaunchP lp) {
  __shared__ u16 smem[2 * 128 * 64];
  int bid = blockIdx.x;
  if (bid < lp.s1) run_job(lp.j[0], bid, smem);
  else if (bid < lp.s2) run_job(lp.j[1], bid - lp.s1, smem);
  else run_job(lp.j[2], bid - lp.s2, smem);
}

// ---- small standalone kernels ----

__global__ __launch_bounds__(256) void pack_m2_k(const float* wy, u16* M2, u16* Bcat) {
  int idx = blockIdx.x * 256 + threadIdx.x;   // 0..262143
  int i = idx >> 9, j = idx & 511;
  u16 a = f2bf(wy[idx]);
  u16 b = f2bf(wy[(long)j * 512 + i]);
  M2[(long)i * 1024 + j] = a;          // [wy | wy^T]
  M2[(long)i * 1024 + 512 + j] = b;
  Bcat[(long)i * 512 + j] = b;         // rows 0..511 of Bcat = wy^T
}

__device__ __forceinline__ float waveRedSum(float v) {
#pragma unroll
  for (int o = 32; o > 0; o >>= 1) v += __shfl_down(v, o, 64);
  return v;
}
__device__ __forceinline__ float waveRedMax(float v) {
#pragma unroll
  for (int o = 32; o > 0; o >>= 1) v = fmaxf(v, __shfl_down(v, o, 64));
  return v;
}

__global__ __launch_bounds__(256) void l2norm_k(const u16* Ycat, u16* pb) {
  __shared__ float red[4];
  int i = blockIdx.x, b = blockIdx.y, t = threadIdx.x;
  const u16* row = Ycat + ((long)b * 4096 + (long)i) * 512;
  unsigned int v = *(const unsigned int*)(row + 2 * t);
  float x0 = bf2f((u16)(v & 0xffff)), x1 = bf2f((u16)(v >> 16));
  float w = waveRedSum(x0 * x0 + x1 * x1);
  if ((t & 63) == 0) red[t >> 6] = w;
  __syncthreads();
  float tot = red[0] + red[1] + red[2] + red[3];
  float inv = 1.f / fmaxf(sqrtf(tot), 1e-12f);
  unsigned int o = (unsigned int)f2bf(x0 * inv) | ((unsigned int)f2bf(x1 * inv) << 16);
  *(unsigned int*)(pb + (long)i * 1536 + b * 512 + 2 * t) = o;
}

// sums 4 split-K logit partials + bias, then log_softmax
__global__ __launch_bounds__(256) void logsoftmax_k(const float* lg, const float* bias, float* out) {
  __shared__ float red[4];
  int i = blockIdx.x, t = threadIdx.x;
  const float* row = lg + (long)i * 512;
  float a  = row[t]       + row[t + SLC]       + row[t + 2 * SLC]       + row[t + 3 * SLC]       + bias[t];
  float b2 = row[t + 256] + row[t + 256 + SLC] + row[t + 256 + 2 * SLC] + row[t + 256 + 3 * SLC] + bias[t + 256];
  float m = waveRedMax(fmaxf(a, b2));
  if ((t & 63) == 0) red[t >> 6] = m;
  __syncthreads();
  float M = fmaxf(fmaxf(red[0], red[1]), fmaxf(red[2], red[3]));
  __syncthreads();
  float w = waveRedSum(__expf(a - M) + __expf(b2 - M));
  if ((t & 63) == 0) red[t >> 6] = w;
  __syncthreads();
  float S = red[0] + red[1] + red[2] + red[3];
  float lse = M + __logf(S);
  out[(long)i * 512 + t] = a - lse;
  out[(long)i * 512 + t + 256] = b2 - lse;
}

extern "C" void kernel_launch(void* const* d_in, const int* in_sizes, int n_in,
                              void* d_out, int out_size, void* d_ws, size_t ws_size,
                              hipStream_t stream) {
  const float* feat = (const float*)d_in[0];
  const float* adj  = (const float*)d_in[1];
  const float* adj1 = (const float*)d_in[2];
  const float* y    = (const float*)d_in[3];
  const float* wy   = (const float*)d_in[4];
  const float* w2w  = (const float*)d_in[5];
  const float* w2b  = (const float*)d_in[6];
  (void)in_sizes; (void)n_in; (void)out_size; (void)ws_size;

  char* ws = (char*)d_ws;
  size_t off = 0;
  auto alloc = [&](size_t bytes) -> void* {
    void* r = ws + off; off += (bytes + 255) & ~(size_t)255; return r;
  };
  u16* M2   = (u16*)alloc(512L * 1024 * 2);        // [wy | wy^T]
  u16* Bcat = (u16*)alloc(1024L * 512 * 2);        // [wy^T rows | Wsum rows]
  u16* adjb = (u16*)alloc(2L * 4096 * 4096 * 2);   // bf16 adj, adj1
  u16* Ycat = (u16*)alloc(3L * 4096 * 512 * 2);    // y,z1,z2 node-major
  u16* Pn   = (u16*)alloc(4096L * 1536 * 2);       // P node-major (scaled)
  u16* XwT  = (u16*)alloc(3L * 512 * 4096 * 2);    // (Ycat@wy)^T; later pb
  u16* TT   = (u16*)alloc(3L * 512 * 4096 * 2);    // (Ycat@Wsum)^T
  u16* Zt   = (u16*)alloc(2L * 512 * 4096 * 2);    // z1^T,z2^T
  u16* Wt   = (u16*)alloc(1536L * 1536 * 2);       // W^T bf16
  float* WU = (float*)alloc(4L * SLC * 4);         // U partials / logit partials
  u16* pb = XwT;

  pack_m2_k<<<1024, 256, 0, stream>>>(wy, M2, Bcat);

  { LaunchP lp = {};   // Wsum gemm (16) || INIT (256)
    Job& a = lp.j[0]; a.mode = MODE_PLAIN; a.gx = 4; a.gy = 4; a.K = 1024;
    a.A0 = a.A1 = M2; a.B = M2; a.lda = 1024; a.ldb = 1024;
    a.C = Bcat + 512L * 512; a.ldc = 512;
    Job& b = lp.j[1]; b.mode = MODE_INIT; b.S0 = y; b.S1 = feat; b.D0 = Ycat;
    lp.s1 = 16; lp.s2 = 272;
    fused_kt<0><<<272, 256, 0, stream>>>(lp); }

  for (int L = 0; L < 2; ++L) {
    { LaunchP lp = {};   // FUSEQT (768) || TRANS (1024) || CVT (512, L0 only)
      Job& a = lp.j[0]; a.mode = MODE_FUSEQT; a.gx = 8; a.gy = 96; a.K = 512;
      a.A0 = a.A1 = Ycat; a.B = Bcat; a.lda = 512; a.ldb = 512;
      a.XwT = XwT; a.TTp = TT; a.Pn = Pn;
      Job& b = lp.j[1]; b.mode = MODE_TRANS; b.A0 = Ycat + SLC; b.bz = SLC;
      b.C = Zt; b.cfz = SLC;
      int grid = 1792;
      lp.s1 = 768; lp.s2 = 1792;
      if (L == 0) {
        Job& c = lp.j[2]; c.mode = MODE_CVT; c.S0 = adj; c.S1 = adj1; c.D0 = adjb;
        grid = 2304;
      }
      fused_kt<1><<<grid, 256, 0, stream>>>(lp); }

    { LaunchP lp = {};   // U partials (512, split-K2) || Wt (144, K=4096)
      Job& a = lp.j[0]; a.mode = MODE_PARTIAL; a.gx = 4; a.gy = 32; a.ksl = 1; a.K = 2048;
      a.A0 = adjb; a.A1 = adjb + 16777216L; a.B = Zt; a.bz = SLC;
      a.lda = 4096; a.ldb = 4096; a.Cf = WU; a.cfz = SLC; a.ldcf = 512;
      Job& b = lp.j[1]; b.mode = MODE_PLAIN; b.gx = 12; b.gy = 12; b.K = 4096;
      b.A0 = b.A1 = TT; b.B = XwT; b.lda = 4096; b.ldb = 4096;
      b.C = Wt; b.ldc = 1536;
      lp.s1 = 512; lp.s2 = 656;
      fused_kt<2><<<656, 256, 0, stream>>>(lp); }

    { LaunchP lp = {};   // SFIN: S = Pn @ Wt^T, fused sigmoid updates into Ycat
      Job& a = lp.j[0]; a.mode = MODE_SFIN; a.gx = 12; a.gy = 32; a.K = 1536;
      a.A0 = a.A1 = Pn; a.B = Wt; a.lda = 1536; a.ldb = 1536;
      a.Ef = feat; a.Up = WU; a.Yc = Ycat;
      lp.s1 = 384; lp.s2 = 384;
      fused_kt<3><<<384, 256, 0, stream>>>(lp); }
  }

  l2norm_k<<<dim3(4096, 3, 1), 256, 0, stream>>>(Ycat, pb);

  { LaunchP lp = {};   // logits split-K4 partials (512 blocks)
    Job& a = lp.j[0]; a.mode = MODE_PARTIAL; a.gx = 4; a.gy = 32; a.ksl = 2; a.K = 384;
    a.A0 = a.A1 = pb; a.Bf = w2w; a.lda = 1536; a.ldb = 1536;
    a.Cf = WU; a.cfz = SLC; a.ldcf = 512;
    lp.s1 = 512; lp.s2 = 512;
    fused_kt<4><<<512, 256, 0, stream>>>(lp); }

  logsoftmax_k<<<4096, 256, 0, stream>>>(WU, w2b, (float*)d_out);
}